// Round 6
// baseline (1019.714 us; speedup 1.0000x reference)
//
#include <hip/hip_runtime.h>
#include <hip/hip_bf16.h>

#define N_NODES 100000
#define N_EDGES 3200000
#define N_GRAPHS 256
#define NB_BUCKETS 196      // ceil(100000 / 512)
#define BSHIFT 9            // 512 nodes per bucket
#define NBLK 256            // blocks for hist/bin passes
#define CHUNK_STRIDE (N_NODES * 8)   // floats per feature-chunk

// ---------------- workspace layout (bytes) ----------------
#define OFF_SUMS      0u            // float[256*64] pool sums (zeroed)
#define OFF_CNTF      65536u        // float[256] pool counts (zeroed)
#define ZERO_BYTES    66560u
#define OFF_HIST      66560u        // int[196*256] (bucket-major) per-(bucket,block) counts
#define OFF_ROWPTR    267264u       // int[N+1]
#define OFF_DINV      667648u       // float[N]
#define OFF_COL       1068032u      // int[E]
#define OFF_XS1       13868032u     // float[N*8]
#define OFF_Z1        17068032u     // float[N*8]
#define OFF_BUFQ      20268032u     // float[N*64] CHUNK-MAJOR: xs2, later z3
#define OFF_BUFR      45868032u     // float[N*64] CHUNK-MAJOR: z2, later ys
#define OFF_BUFP      71468032u     // float[N*128] h2 row-major; ALIASED: int2 pairs[E]
#define OFF_PAIRS     OFF_BUFP
// total ~122.7 MB

__global__ void zero_kernel(int* p, int n) {
    int i = blockIdx.x * 256 + threadIdx.x;
    if (i < n) p[i] = 0;
}

// ---- P1: per-(bucket,block) histogram of dst. No global atomics.
__global__ __launch_bounds__(256) void hist_kernel(const int* __restrict__ dst,
                                                   int* __restrict__ hist, int E, int epb) {
    __shared__ int h[NB_BUCKETS];
    int t = threadIdx.x, blk = blockIdx.x;
    if (t < NB_BUCKETS) h[t] = 0;
    __syncthreads();
    int e0 = blk * epb, e1 = min(e0 + epb, E);
    for (int e = e0 + t; e < e1; e += 256)
        atomicAdd(&h[__builtin_nontemporal_load(&dst[e]) >> BSHIFT], 1);
    __syncthreads();
    if (t < NB_BUCKETS) hist[t * NBLK + blk] = h[t];
}

// ---- P2: in-place exclusive scan of hist[196*256] (bucket-major).
__global__ __launch_bounds__(1024) void scanhist_kernel(int* __restrict__ hist) {
    const int TOT = NB_BUCKETS * NBLK;     // 50176 = 1024*49
    const int CH = TOT / 1024;             // 49
    __shared__ int s[1024];
    int t = threadIdx.x;
    int base = t * CH;
    int sum = 0;
    for (int j = 0; j < CH; ++j) sum += hist[base + j];
    int v = sum;
    s[t] = v;
    __syncthreads();
    for (int off = 1; off < 1024; off <<= 1) {
        int add = (t >= off) ? s[t - off] : 0;
        __syncthreads();
        s[t] += add;
        __syncthreads();
    }
    int run = s[t] - v;                    // exclusive prefix of this chunk
    for (int j = 0; j < CH; ++j) {
        int tmp = hist[base + j];
        hist[base + j] = run;
        run += tmp;
    }
}

// ---- P3: bin edges into bucket-grouped (src,dst) pairs.
__global__ __launch_bounds__(256) void bin_kernel(const int* __restrict__ src,
                                                  const int* __restrict__ dst,
                                                  const int* __restrict__ hist,
                                                  int2* __restrict__ pairs, int E, int epb) {
    __shared__ int cur[NB_BUCKETS];
    int t = threadIdx.x, blk = blockIdx.x;
    if (t < NB_BUCKETS) cur[t] = hist[t * NBLK + blk];
    __syncthreads();
    int e0 = blk * epb, e1 = min(e0 + epb, E);
    for (int e = e0 + t; e < e1; e += 256) {
        int d = __builtin_nontemporal_load(&dst[e]);
        int sv = __builtin_nontemporal_load(&src[e]);
        int pos = atomicAdd(&cur[d >> BSHIFT], 1);
        pairs[pos] = make_int2(sv, d);
    }
}

// ---- P4: per-bucket CSR finalize (row_ptr, dinv, col) with LDS counters.
__global__ __launch_bounds__(512) void csr_kernel(const int2* __restrict__ pairs,
                                                  const int* __restrict__ hist,
                                                  int* __restrict__ row_ptr,
                                                  float* __restrict__ dinv,
                                                  int* __restrict__ col, int E) {
    __shared__ int cntL[512];
    __shared__ int rsL[512];
    __shared__ int fillL[512];
    int t = threadIdx.x, b = blockIdx.x;
    int lo = b << BSHIFT;
    int nloc = min(512, N_NODES - lo);
    int start = hist[b * NBLK];
    int end = (b == NB_BUCKETS - 1) ? E : hist[(b + 1) * NBLK];
    cntL[t] = 0;
    fillL[t] = 0;
    __syncthreads();
    for (int e = start + t; e < end; e += 512)
        atomicAdd(&cntL[pairs[e].y - lo], 1);
    __syncthreads();
    int v = cntL[t];
    __syncthreads();
    for (int off = 1; off < 512; off <<= 1) {     // inclusive scan (Hillis-Steele)
        int add = (t >= off) ? cntL[t - off] : 0;
        __syncthreads();
        cntL[t] += add;
        __syncthreads();
    }
    int rowstart = start + cntL[t] - v;           // exclusive + bucket base
    rsL[t] = rowstart;
    if (t < nloc) {
        row_ptr[lo + t] = rowstart;
        dinv[lo + t] = rsqrtf((float)(v + 1));
    }
    if (b == NB_BUCKETS - 1 && t == 0) row_ptr[N_NODES] = E;
    __syncthreads();
    for (int e = start + t; e < end; e += 512) {
        int2 p = pairs[e];
        int dl = p.y - lo;
        int pos = rsL[dl] + atomicAdd(&fillL[dl], 1);
        col[pos] = p.x;
    }
}

__global__ void scale_x8_kernel(const float* __restrict__ x, const float* __restrict__ dinv,
                                float* __restrict__ xs, int n8) {
    int i = blockIdx.x * 256 + threadIdx.x;
    if (i < n8) xs[i] = x[i] * dinv[i >> 3];
}

// Layer-1 aggregation (D=8, row-major [N,8] -- 3.2 MB, already L2-resident).
__global__ void agg8_kernel(const float* __restrict__ xs, const int* __restrict__ row_ptr,
                            const int* __restrict__ col, const float* __restrict__ dinv,
                            float* __restrict__ z, int n) {
    int node = blockIdx.x * 32 + threadIdx.x / 8;
    int f = threadIdx.x % 8;
    if (node >= n) return;
    int e0 = row_ptr[node], e1 = row_ptr[node + 1];
    float a0 = xs[node * 8 + f], a1 = 0.f, a2 = 0.f, a3 = 0.f;
    int e = e0;
    for (; e + 4 <= e1; e += 4) {
        int s0 = __builtin_nontemporal_load(&col[e]);
        int s1 = __builtin_nontemporal_load(&col[e + 1]);
        int s2 = __builtin_nontemporal_load(&col[e + 2]);
        int s3 = __builtin_nontemporal_load(&col[e + 3]);
        a0 += xs[s0 * 8 + f];
        a1 += xs[s1 * 8 + f];
        a2 += xs[s2 * 8 + f];
        a3 += xs[s3 * 8 + f];
    }
    for (; e < e1; ++e) a0 += xs[__builtin_nontemporal_load(&col[e]) * 8 + f];
    z[node * 8 + f] = dinv[node] * ((a0 + a1) + (a2 + a3));
}

// Feature-CHUNKED D=64 aggregation: 8 passes of 8 features, chunk-major
// buffers. Each pass's gather array is 3.2 MB -> fully L2-resident per XCD
// (was: 25.6 MB working set, 399 MB fabric fetch, 2.7 TB/s bound).
// gridDim.x = 8 with chunk = blockIdx.x: under round-robin block->XCD
// dispatch this pins chunk c to XCD c (locality heuristic only).
__global__ __launch_bounds__(256) void aggc_kernel(const float* __restrict__ xs,
                                                   const int* __restrict__ row_ptr,
                                                   const int* __restrict__ col,
                                                   const float* __restrict__ dinv,
                                                   float* __restrict__ z, int n) {
    int chunk = blockIdx.x;                       // 0..7
    int node = blockIdx.y * 32 + (threadIdx.x >> 3);
    int j = threadIdx.x & 7;
    if (node >= n) return;
    const float* xc = xs + chunk * CHUNK_STRIDE;
    float* zc = z + chunk * CHUNK_STRIDE;
    int e0 = row_ptr[node], e1 = row_ptr[node + 1];
    float a0 = xc[node * 8 + j], a1 = 0.f, a2 = 0.f, a3 = 0.f;
    int e = e0;
    for (; e + 4 <= e1; e += 4) {
        int s0 = __builtin_nontemporal_load(&col[e]);
        int s1 = __builtin_nontemporal_load(&col[e + 1]);
        int s2 = __builtin_nontemporal_load(&col[e + 2]);
        int s3 = __builtin_nontemporal_load(&col[e + 3]);
        a0 += xc[s0 * 8 + j];
        a1 += xc[s1 * 8 + j];
        a2 += xc[s2 * 8 + j];
        a3 += xc[s3 * 8 + j];
    }
    for (; e < e1; ++e) a0 += xc[__builtin_nontemporal_load(&col[e]) * 8 + j];
    zc[node * 8 + j] = dinv[node] * ((a0 + a1) + (a2 + a3));
}

// Y[row, :] = opt_scale(dinv[row]) * opt_relu( X[row,:] @ W + opt_bias )
// IN_CM: X is chunk-major [8][N][8] (requires K==64).
// OUT_CM: Y written chunk-major (requires M==64).
template <int K, int M, bool BIAS, bool RELU, bool SCALE, bool IN_CM, bool OUT_CM>
__global__ __launch_bounds__(256) void gemm_kernel(
        const float* __restrict__ X, const float* __restrict__ W,
        const float* __restrict__ b, const float* __restrict__ dinv,
        float* __restrict__ Y, int nrows) {
    constexpr int CG = M / 4;        // column groups of 4 (float4)
    constexpr int ROWS = 256 / CG;   // rows per tile
    __shared__ float Wl[K * M];
    __shared__ float Bl[M];
    __shared__ float Xl[ROWS * K];
    int tid = threadIdx.x;
    for (int i = tid; i < K * M; i += 256) Wl[i] = W[i];
    if (tid < M) {
        if constexpr (BIAS) Bl[tid] = b[tid];
        else Bl[tid] = 0.0f;
    }
    int ntiles = (nrows + ROWS - 1) / ROWS;
    for (int tile = blockIdx.x; tile < ntiles; tile += gridDim.x) {
        int row0 = tile * ROWS;
        __syncthreads();
        for (int i = tid; i < ROWS * K; i += 256) {
            float v = 0.0f;
            if constexpr (IN_CM) {
                int rr = i / K, f = i % K;           // K == 64
                int row = row0 + rr;
                if (row < nrows)
                    v = X[(f >> 3) * CHUNK_STRIDE + row * 8 + (f & 7)];
            } else {
                int gi = row0 * K + i;
                if (gi < nrows * K) v = X[gi];
            }
            Xl[i] = v;
        }
        __syncthreads();
        int r = tid / CG, cg = tid % CG;
        int row = row0 + r;
        if (row < nrows) {
            float4 acc;
            acc.x = Bl[cg * 4 + 0];
            acc.y = Bl[cg * 4 + 1];
            acc.z = Bl[cg * 4 + 2];
            acc.w = Bl[cg * 4 + 3];
#pragma unroll
            for (int k = 0; k < K; ++k) {
                float xv = Xl[r * K + k];
                const float4 w = *reinterpret_cast<const float4*>(&Wl[k * M + cg * 4]);
                acc.x += xv * w.x;
                acc.y += xv * w.y;
                acc.z += xv * w.z;
                acc.w += xv * w.w;
            }
            if constexpr (RELU) {
                acc.x = fmaxf(acc.x, 0.f); acc.y = fmaxf(acc.y, 0.f);
                acc.z = fmaxf(acc.z, 0.f); acc.w = fmaxf(acc.w, 0.f);
            }
            if constexpr (SCALE) {
                float d = dinv[row];
                acc.x *= d; acc.y *= d; acc.z *= d; acc.w *= d;
            }
            if constexpr (OUT_CM) {   // M == 64: chunk = cg>>1, j0 = (cg&1)*4
                *reinterpret_cast<float4*>(
                    &Y[(cg >> 1) * CHUNK_STRIDE + row * 8 + (cg & 1) * 4]) = acc;
            } else {
                *reinterpret_cast<float4*>(&Y[row * M + cg * 4]) = acc;
            }
        }
    }
}

// h3 = relu(z3 + b3); pool sums/counts per graph (batch sorted ->
// register-accumulate per graph-run). z3 is chunk-major.
#define POOL_NPB 1024   // nodes per block
__global__ __launch_bounds__(256) void pool_kernel(
        const float* __restrict__ z3, const float* __restrict__ b3,
        const int* __restrict__ batch, float* __restrict__ sums,
        float* __restrict__ cntf, int n) {
    int wave = threadIdx.x >> 6;
    int lane = threadIdx.x & 63;   // feature index
    int node0 = blockIdx.x * POOL_NPB;
    int nodeEnd = node0 + POOL_NPB;
    if (nodeEnd > n) nodeEnd = n;
    float bias = b3[lane];
    const float* zc = z3 + (lane >> 3) * CHUNK_STRIDE + (lane & 7);
    float acc = 0.0f, cnt = 0.0f;
    int curg = -1;
    for (int node = node0 + wave; node < nodeEnd; node += 4) {
        int g = batch[node];               // wave-uniform (lane = feature)
        if (g != curg) {                   // wave-uniform branch
            if (curg >= 0) {
                atomicAdd(&sums[curg * 64 + lane], acc);
                if (lane == 0) atomicAdd(&cntf[curg], cnt);
            }
            curg = g; acc = 0.0f; cnt = 0.0f;
        }
        acc += fmaxf(__builtin_nontemporal_load(&zc[node * 8]) + bias, 0.0f);
        cnt += 1.0f;
    }
    if (curg >= 0) {
        atomicAdd(&sums[curg * 64 + lane], acc);
        if (lane == 0) atomicAdd(&cntf[curg], cnt);
    }
}

// per-graph: g = sums/max(cnt,1); hid = relu(g@Wl1+bl1); out = hid@Wl2+bl2
__global__ void mlp_kernel(const float* __restrict__ sums, const float* __restrict__ cntf,
                           const float* __restrict__ Wl1, const float* __restrict__ bl1,
                           const float* __restrict__ Wl2, const float* __restrict__ bl2,
                           float* __restrict__ out) {
    __shared__ float gv[64];
    __shared__ float hid[32];
    int g = blockIdx.x, t = threadIdx.x;
    float denom = fmaxf(cntf[g], 1.0f);
    gv[t] = sums[g * 64 + t] / denom;
    __syncthreads();
    if (t < 32) {
        float a = bl1[t];
#pragma unroll
        for (int k = 0; k < 64; ++k) a += gv[k] * Wl1[k * 32 + t];
        hid[t] = fmaxf(a, 0.0f);
    }
    __syncthreads();
    if (t == 0) {
        float o = bl2[0];
#pragma unroll
        for (int k = 0; k < 32; ++k) o += hid[k] * Wl2[k];
        out[g] = o;
    }
}

extern "C" void kernel_launch(void* const* d_in, const int* in_sizes, int n_in,
                              void* d_out, int out_size, void* d_ws, size_t ws_size,
                              hipStream_t stream) {
    const float* x   = (const float*)d_in[0];
    const int* ei    = (const int*)d_in[1];
    const int* batch = (const int*)d_in[2];
    const float* W1  = (const float*)d_in[3];
    const float* b1  = (const float*)d_in[4];
    const float* W2  = (const float*)d_in[5];
    const float* b2  = (const float*)d_in[6];
    const float* W3  = (const float*)d_in[7];
    const float* b3  = (const float*)d_in[8];
    const float* Wl1 = (const float*)d_in[9];
    const float* bl1 = (const float*)d_in[10];
    const float* Wl2 = (const float*)d_in[11];
    const float* bl2 = (const float*)d_in[12];
    float* out = (float*)d_out;

    const int N = N_NODES;
    const int E = in_sizes[1] / 2;   // 3.2M
    const int* src = ei;
    const int* dst = ei + E;

    char* ws = (char*)d_ws;
    float* sums    = (float*)(ws + OFF_SUMS);
    float* cntf    = (float*)(ws + OFF_CNTF);
    int*   hist    = (int*)(ws + OFF_HIST);
    int*   row_ptr = (int*)(ws + OFF_ROWPTR);
    float* dinv    = (float*)(ws + OFF_DINV);
    int*   col     = (int*)(ws + OFF_COL);
    float* xs1     = (float*)(ws + OFF_XS1);
    float* z1      = (float*)(ws + OFF_Z1);
    float* bufQ    = (float*)(ws + OFF_BUFQ);   // xs2, later z3 (chunk-major)
    float* bufR    = (float*)(ws + OFF_BUFR);   // z2, later ys (chunk-major)
    float* bufP    = (float*)(ws + OFF_BUFP);   // h2 row-major
    int2*  pairs   = (int2*)(ws + OFF_PAIRS);   // aliases bufP (dead before h2)

    // zero pool accumulators
    zero_kernel<<<(ZERO_BYTES / 4 + 255) / 256, 256, 0, stream>>>((int*)ws, ZERO_BYTES / 4);

    // CSR build: hist -> scan -> bin -> per-bucket finalize
    int epb = (E + NBLK - 1) / NBLK;   // 12500
    hist_kernel<<<NBLK, 256, 0, stream>>>(dst, hist, E, epb);
    scanhist_kernel<<<1, 1024, 0, stream>>>(hist);
    bin_kernel<<<NBLK, 256, 0, stream>>>(src, dst, hist, pairs, E, epb);
    csr_kernel<<<NB_BUCKETS, 512, 0, stream>>>(pairs, hist, row_ptr, dinv, col, E);

    // Layer 1: xs1 = dinv*x ; z1 = agg(xs1) ; xs2 = dinv*relu(z1@W1+b1) [CM out]
    scale_x8_kernel<<<(N * 8 + 255) / 256, 256, 0, stream>>>(x, dinv, xs1, N * 8);
    agg8_kernel<<<(N + 31) / 32, 256, 0, stream>>>(xs1, row_ptr, col, dinv, z1, N);
    gemm_kernel<8, 64, true, true, true, false, true>
        <<<2560, 256, 0, stream>>>(z1, W1, b1, dinv, bufQ, N);

    // Layer 2: z2 = agg(xs2) [CM] ; h2 = relu(z2@W2+b2) [CM in, RM out]
    aggc_kernel<<<dim3(8, (N + 31) / 32), 256, 0, stream>>>(bufQ, row_ptr, col, dinv, bufR, N);
    gemm_kernel<64, 128, true, true, false, true, false>
        <<<2560, 256, 0, stream>>>(bufR, W2, b2, nullptr, bufP, N);

    // Layer 3: ys = dinv*(h2@W3) [RM in, CM out] ; z3 = agg(ys) [CM]
    gemm_kernel<128, 64, false, false, true, false, true>
        <<<2560, 256, 0, stream>>>(bufP, W3, nullptr, dinv, bufR, N);
    aggc_kernel<<<dim3(8, (N + 31) / 32), 256, 0, stream>>>(bufR, row_ptr, col, dinv, bufQ, N);

    // Pool + MLP head
    pool_kernel<<<(N + POOL_NPB - 1) / POOL_NPB, 256, 0, stream>>>(bufQ, b3, batch, sums, cntf, N);
    mlp_kernel<<<N_GRAPHS, 64, 0, stream>>>(sums, cntf, Wl1, bl1, Wl2, bl2, out);
}

// Round 7
// 689.300 us; speedup vs baseline: 1.4793x; 1.4793x over previous
//
#include <hip/hip_runtime.h>
#include <hip/hip_bf16.h>

#define N_NODES 100000
#define N_EDGES 3200000
#define N_GRAPHS 256
#define NB_BUCKETS 196      // ceil(100000 / 512)
#define BSHIFT 9            // 512 nodes per bucket
#define NBLK 256            // blocks for hist/bin passes

// ---------------- workspace layout (bytes) ----------------
#define OFF_SUMS      0u            // float[256*64] pool sums (zeroed)
#define OFF_CNTF      65536u        // float[256] pool counts (zeroed)
#define ZERO_BYTES    66560u
#define OFF_HIST      66560u        // int[196*256] (bucket-major) per-(bucket,block) counts
#define OFF_ROWPTR    267264u       // int[N+1]
#define OFF_DINV      667648u       // float[N]
#define OFF_COL       1068032u      // int[E]
#define OFF_XS1       13868032u     // float[N*8]
#define OFF_Z1        17068032u     // float[N*8]
#define OFF_BUFQ      20268032u     // float[N*64]  xs2, later z3
#define OFF_BUFR      45868032u     // float[N*64]  z2, later ys
#define OFF_BUFP      71468032u     // float[N*128] h2; ALIASED: int2 pairs[E]
#define OFF_PAIRS     OFF_BUFP
// total ~122.7 MB

__global__ void zero_kernel(int* p, int n) {
    int i = blockIdx.x * 256 + threadIdx.x;
    if (i < n) p[i] = 0;
}

// ---- P1: per-(bucket,block) histogram of dst. No global atomics.
__global__ __launch_bounds__(256) void hist_kernel(const int* __restrict__ dst,
                                                   int* __restrict__ hist, int E, int epb) {
    __shared__ int h[NB_BUCKETS];
    int t = threadIdx.x, blk = blockIdx.x;
    if (t < NB_BUCKETS) h[t] = 0;
    __syncthreads();
    int e0 = blk * epb, e1 = min(e0 + epb, E);
    for (int e = e0 + t; e < e1; e += 256)
        atomicAdd(&h[__builtin_nontemporal_load(&dst[e]) >> BSHIFT], 1);
    __syncthreads();
    if (t < NB_BUCKETS) hist[t * NBLK + blk] = h[t];
}

// ---- P2: in-place exclusive scan of hist[196*256] (bucket-major).
__global__ __launch_bounds__(1024) void scanhist_kernel(int* __restrict__ hist) {
    const int TOT = NB_BUCKETS * NBLK;     // 50176 = 1024*49
    const int CH = TOT / 1024;             // 49
    __shared__ int s[1024];
    int t = threadIdx.x;
    int base = t * CH;
    int sum = 0;
    for (int j = 0; j < CH; ++j) sum += hist[base + j];
    int v = sum;
    s[t] = v;
    __syncthreads();
    for (int off = 1; off < 1024; off <<= 1) {
        int add = (t >= off) ? s[t - off] : 0;
        __syncthreads();
        s[t] += add;
        __syncthreads();
    }
    int run = s[t] - v;                    // exclusive prefix of this chunk
    for (int j = 0; j < CH; ++j) {
        int tmp = hist[base + j];
        hist[base + j] = run;
        run += tmp;
    }
}

// ---- P3: bin edges into bucket-grouped (src,dst) pairs.
__global__ __launch_bounds__(256) void bin_kernel(const int* __restrict__ src,
                                                  const int* __restrict__ dst,
                                                  const int* __restrict__ hist,
                                                  int2* __restrict__ pairs, int E, int epb) {
    __shared__ int cur[NB_BUCKETS];
    int t = threadIdx.x, blk = blockIdx.x;
    if (t < NB_BUCKETS) cur[t] = hist[t * NBLK + blk];
    __syncthreads();
    int e0 = blk * epb, e1 = min(e0 + epb, E);
    for (int e = e0 + t; e < e1; e += 256) {
        int d = __builtin_nontemporal_load(&dst[e]);
        int sv = __builtin_nontemporal_load(&src[e]);
        int pos = atomicAdd(&cur[d >> BSHIFT], 1);
        pairs[pos] = make_int2(sv, d);
    }
}

// ---- P4: per-bucket CSR finalize (row_ptr, dinv, col) with LDS counters.
__global__ __launch_bounds__(512) void csr_kernel(const int2* __restrict__ pairs,
                                                  const int* __restrict__ hist,
                                                  int* __restrict__ row_ptr,
                                                  float* __restrict__ dinv,
                                                  int* __restrict__ col, int E) {
    __shared__ int cntL[512];
    __shared__ int rsL[512];
    __shared__ int fillL[512];
    int t = threadIdx.x, b = blockIdx.x;
    int lo = b << BSHIFT;
    int nloc = min(512, N_NODES - lo);
    int start = hist[b * NBLK];
    int end = (b == NB_BUCKETS - 1) ? E : hist[(b + 1) * NBLK];
    cntL[t] = 0;
    fillL[t] = 0;
    __syncthreads();
    for (int e = start + t; e < end; e += 512)
        atomicAdd(&cntL[pairs[e].y - lo], 1);
    __syncthreads();
    int v = cntL[t];
    __syncthreads();
    for (int off = 1; off < 512; off <<= 1) {     // inclusive scan (Hillis-Steele)
        int add = (t >= off) ? cntL[t - off] : 0;
        __syncthreads();
        cntL[t] += add;
        __syncthreads();
    }
    int rowstart = start + cntL[t] - v;           // exclusive + bucket base
    rsL[t] = rowstart;
    if (t < nloc) {
        row_ptr[lo + t] = rowstart;
        dinv[lo + t] = rsqrtf((float)(v + 1));
    }
    if (b == NB_BUCKETS - 1 && t == 0) row_ptr[N_NODES] = E;
    __syncthreads();
    for (int e = start + t; e < end; e += 512) {
        int2 p = pairs[e];
        int dl = p.y - lo;
        int pos = rsL[dl] + atomicAdd(&fillL[dl], 1);
        col[pos] = p.x;
    }
}

__global__ void scale_x8_kernel(const float* __restrict__ x, const float* __restrict__ dinv,
                                float* __restrict__ xs, int n8) {
    int i = blockIdx.x * 256 + threadIdx.x;
    if (i < n8) xs[i] = x[i] * dinv[i >> 3];
}

// z_i[f] = dinv_i * ( xs_i[f] + sum_{e in CSR row i} xs[col[e]][f] )
// One wave covers one node's D features (D=64) -> each edge is ONE coalesced
// 256 B gather. Unroll-8 keeps 8 gathers in flight per wave (was 4) to raise
// memory-level parallelism on the L2-miss path.
template <int D>
__global__ void agg_kernel(const float* __restrict__ xs, const int* __restrict__ row_ptr,
                           const int* __restrict__ col, const float* __restrict__ dinv,
                           float* __restrict__ z, int n) {
    constexpr int GROUPS = 256 / D;
    int node = blockIdx.x * GROUPS + threadIdx.x / D;
    int f = threadIdx.x % D;
    if (node >= n) return;
    int e0 = row_ptr[node], e1 = row_ptr[node + 1];
    float a0 = xs[node * D + f], a1 = 0.f, a2 = 0.f, a3 = 0.f;
    float a4 = 0.f, a5 = 0.f, a6 = 0.f, a7 = 0.f;
    int e = e0;
    for (; e + 8 <= e1; e += 8) {
        int s0 = __builtin_nontemporal_load(&col[e]);
        int s1 = __builtin_nontemporal_load(&col[e + 1]);
        int s2 = __builtin_nontemporal_load(&col[e + 2]);
        int s3 = __builtin_nontemporal_load(&col[e + 3]);
        int s4 = __builtin_nontemporal_load(&col[e + 4]);
        int s5 = __builtin_nontemporal_load(&col[e + 5]);
        int s6 = __builtin_nontemporal_load(&col[e + 6]);
        int s7 = __builtin_nontemporal_load(&col[e + 7]);
        a0 += xs[s0 * D + f];
        a1 += xs[s1 * D + f];
        a2 += xs[s2 * D + f];
        a3 += xs[s3 * D + f];
        a4 += xs[s4 * D + f];
        a5 += xs[s5 * D + f];
        a6 += xs[s6 * D + f];
        a7 += xs[s7 * D + f];
    }
    for (; e < e1; ++e) a0 += xs[__builtin_nontemporal_load(&col[e]) * D + f];
    float r = ((a0 + a1) + (a2 + a3)) + ((a4 + a5) + (a6 + a7));
    z[node * D + f] = dinv[node] * r;
}

// Y[row, :] = opt_scale(dinv[row]) * opt_relu( X[row,:] @ W + opt_bias )
template <int K, int M, bool BIAS, bool RELU, bool SCALE>
__global__ __launch_bounds__(256) void gemm_kernel(
        const float* __restrict__ X, const float* __restrict__ W,
        const float* __restrict__ b, const float* __restrict__ dinv,
        float* __restrict__ Y, int nrows) {
    constexpr int CG = M / 4;        // column groups of 4 (float4)
    constexpr int ROWS = 256 / CG;   // rows per tile
    __shared__ float Wl[K * M];
    __shared__ float Bl[M];
    __shared__ float Xl[ROWS * K];
    int tid = threadIdx.x;
    for (int i = tid; i < K * M; i += 256) Wl[i] = W[i];
    if (tid < M) {
        if constexpr (BIAS) Bl[tid] = b[tid];
        else Bl[tid] = 0.0f;
    }
    int ntiles = (nrows + ROWS - 1) / ROWS;
    for (int tile = blockIdx.x; tile < ntiles; tile += gridDim.x) {
        int row0 = tile * ROWS;
        __syncthreads();
        for (int i = tid; i < ROWS * K; i += 256) {
            int gi = row0 * K + i;
            Xl[i] = (gi < nrows * K) ? X[gi] : 0.0f;
        }
        __syncthreads();
        int r = tid / CG, cg = tid % CG;
        int row = row0 + r;
        if (row < nrows) {
            float4 acc;
            acc.x = Bl[cg * 4 + 0];
            acc.y = Bl[cg * 4 + 1];
            acc.z = Bl[cg * 4 + 2];
            acc.w = Bl[cg * 4 + 3];
#pragma unroll
            for (int k = 0; k < K; ++k) {
                float xv = Xl[r * K + k];
                const float4 w = *reinterpret_cast<const float4*>(&Wl[k * M + cg * 4]);
                acc.x += xv * w.x;
                acc.y += xv * w.y;
                acc.z += xv * w.z;
                acc.w += xv * w.w;
            }
            if constexpr (RELU) {
                acc.x = fmaxf(acc.x, 0.f); acc.y = fmaxf(acc.y, 0.f);
                acc.z = fmaxf(acc.z, 0.f); acc.w = fmaxf(acc.w, 0.f);
            }
            if constexpr (SCALE) {
                float d = dinv[row];
                acc.x *= d; acc.y *= d; acc.z *= d; acc.w *= d;
            }
            *reinterpret_cast<float4*>(&Y[row * M + cg * 4]) = acc;
        }
    }
}

// h3 = relu(z3 + b3); pool sums/counts per graph (batch sorted ->
// register-accumulate per graph-run, ~90K atomics total).
#define POOL_NPB 1024   // nodes per block
__global__ __launch_bounds__(256) void pool_kernel(
        const float* __restrict__ z3, const float* __restrict__ b3,
        const int* __restrict__ batch, float* __restrict__ sums,
        float* __restrict__ cntf, int n) {
    int wave = threadIdx.x >> 6;
    int lane = threadIdx.x & 63;   // feature index
    int node0 = blockIdx.x * POOL_NPB;
    int nodeEnd = node0 + POOL_NPB;
    if (nodeEnd > n) nodeEnd = n;
    float bias = b3[lane];
    float acc = 0.0f, cnt = 0.0f;
    int curg = -1;
    for (int node = node0 + wave; node < nodeEnd; node += 4) {
        int g = batch[node];               // wave-uniform (lane = feature)
        if (g != curg) {                   // wave-uniform branch
            if (curg >= 0) {
                atomicAdd(&sums[curg * 64 + lane], acc);
                if (lane == 0) atomicAdd(&cntf[curg], cnt);
            }
            curg = g; acc = 0.0f; cnt = 0.0f;
        }
        acc += fmaxf(__builtin_nontemporal_load(&z3[node * 64 + lane]) + bias, 0.0f);
        cnt += 1.0f;
    }
    if (curg >= 0) {
        atomicAdd(&sums[curg * 64 + lane], acc);
        if (lane == 0) atomicAdd(&cntf[curg], cnt);
    }
}

// per-graph: g = sums/max(cnt,1); hid = relu(g@Wl1+bl1); out = hid@Wl2+bl2
__global__ void mlp_kernel(const float* __restrict__ sums, const float* __restrict__ cntf,
                           const float* __restrict__ Wl1, const float* __restrict__ bl1,
                           const float* __restrict__ Wl2, const float* __restrict__ bl2,
                           float* __restrict__ out) {
    __shared__ float gv[64];
    __shared__ float hid[32];
    int g = blockIdx.x, t = threadIdx.x;
    float denom = fmaxf(cntf[g], 1.0f);
    gv[t] = sums[g * 64 + t] / denom;
    __syncthreads();
    if (t < 32) {
        float a = bl1[t];
#pragma unroll
        for (int k = 0; k < 64; ++k) a += gv[k] * Wl1[k * 32 + t];
        hid[t] = fmaxf(a, 0.0f);
    }
    __syncthreads();
    if (t == 0) {
        float o = bl2[0];
#pragma unroll
        for (int k = 0; k < 32; ++k) o += hid[k] * Wl2[k];
        out[g] = o;
    }
}

extern "C" void kernel_launch(void* const* d_in, const int* in_sizes, int n_in,
                              void* d_out, int out_size, void* d_ws, size_t ws_size,
                              hipStream_t stream) {
    const float* x   = (const float*)d_in[0];
    const int* ei    = (const int*)d_in[1];
    const int* batch = (const int*)d_in[2];
    const float* W1  = (const float*)d_in[3];
    const float* b1  = (const float*)d_in[4];
    const float* W2  = (const float*)d_in[5];
    const float* b2  = (const float*)d_in[6];
    const float* W3  = (const float*)d_in[7];
    const float* b3  = (const float*)d_in[8];
    const float* Wl1 = (const float*)d_in[9];
    const float* bl1 = (const float*)d_in[10];
    const float* Wl2 = (const float*)d_in[11];
    const float* bl2 = (const float*)d_in[12];
    float* out = (float*)d_out;

    const int N = N_NODES;
    const int E = in_sizes[1] / 2;   // 3.2M
    const int* src = ei;
    const int* dst = ei + E;

    char* ws = (char*)d_ws;
    float* sums    = (float*)(ws + OFF_SUMS);
    float* cntf    = (float*)(ws + OFF_CNTF);
    int*   hist    = (int*)(ws + OFF_HIST);
    int*   row_ptr = (int*)(ws + OFF_ROWPTR);
    float* dinv    = (float*)(ws + OFF_DINV);
    int*   col     = (int*)(ws + OFF_COL);
    float* xs1     = (float*)(ws + OFF_XS1);
    float* z1      = (float*)(ws + OFF_Z1);
    float* bufQ    = (float*)(ws + OFF_BUFQ);   // xs2, later z3
    float* bufR    = (float*)(ws + OFF_BUFR);   // z2, later ys
    float* bufP    = (float*)(ws + OFF_BUFP);   // h2
    int2*  pairs   = (int2*)(ws + OFF_PAIRS);   // aliases bufP (dead before h2)

    // zero pool accumulators
    zero_kernel<<<(ZERO_BYTES / 4 + 255) / 256, 256, 0, stream>>>((int*)ws, ZERO_BYTES / 4);

    // CSR build: hist -> scan -> bin -> per-bucket finalize
    int epb = (E + NBLK - 1) / NBLK;   // 12500
    hist_kernel<<<NBLK, 256, 0, stream>>>(dst, hist, E, epb);
    scanhist_kernel<<<1, 1024, 0, stream>>>(hist);
    bin_kernel<<<NBLK, 256, 0, stream>>>(src, dst, hist, pairs, E, epb);
    csr_kernel<<<NB_BUCKETS, 512, 0, stream>>>(pairs, hist, row_ptr, dinv, col, E);

    // Layer 1: xs1 = dinv*x ; z1 = agg(xs1) ; xs2 = dinv*relu(z1@W1+b1)
    scale_x8_kernel<<<(N * 8 + 255) / 256, 256, 0, stream>>>(x, dinv, xs1, N * 8);
    agg_kernel<8><<<(N + 31) / 32, 256, 0, stream>>>(xs1, row_ptr, col, dinv, z1, N);
    gemm_kernel<8, 64, true, true, true><<<2560, 256, 0, stream>>>(z1, W1, b1, dinv, bufQ, N);

    // Layer 2: z2 = agg(xs2) ; h2 = relu(z2@W2+b2)
    agg_kernel<64><<<(N + 3) / 4, 256, 0, stream>>>(bufQ, row_ptr, col, dinv, bufR, N);
    gemm_kernel<64, 128, true, true, false><<<2560, 256, 0, stream>>>(bufR, W2, b2, nullptr, bufP, N);

    // Layer 3: ys = dinv*(h2@W3) ; z3 = agg(ys)
    gemm_kernel<128, 64, false, false, true><<<2560, 256, 0, stream>>>(bufP, W3, nullptr, dinv, bufR, N);
    agg_kernel<64><<<(N + 3) / 4, 256, 0, stream>>>(bufR, row_ptr, col, dinv, bufQ, N);

    // Pool + MLP head
    pool_kernel<<<(N + POOL_NPB - 1) / POOL_NPB, 256, 0, stream>>>(bufQ, b3, batch, sums, cntf, N);
    mlp_kernel<<<N_GRAPHS, 64, 0, stream>>>(sums, cntf, Wl1, bl1, Wl2, bl2, out);
}

// Round 8
// 669.444 us; speedup vs baseline: 1.5232x; 1.0297x over previous
//
#include <hip/hip_runtime.h>
#include <hip/hip_bf16.h>

#define N_NODES 100000
#define N_EDGES 3200000
#define N_GRAPHS 256
#define NB_BUCKETS 196      // ceil(100000 / 512)
#define BSHIFT 9            // 512 nodes per bucket
#define NBLK 256            // blocks for hist/bin passes

// ---------------- workspace layout (bytes) ----------------
#define OFF_SUMS      0u            // float[256*64] pool sums (zeroed)
#define OFF_CNTF      65536u        // float[256] pool counts (zeroed)
#define ZERO_BYTES    66560u
#define OFF_HIST      66560u        // int[196*256] (bucket-major) per-(bucket,block) counts
#define OFF_ROWPTR    267264u       // int[N+1]
#define OFF_DINV      667648u       // float[N]
#define OFF_COL       1068032u      // int[E]
#define OFF_XS1       13868032u     // float[N*8]
#define OFF_Z1        17068032u     // float[N*8]
#define OFF_BUFQ      20268032u     // float[N*64]  xs2, later z3
#define OFF_BUFR      45868032u     // float[N*64]  z2, later ys
#define OFF_BUFP      71468032u     // float[N*128] h2; ALIASED: int2 pairs[E]
#define OFF_PAIRS     OFF_BUFP
// total ~122.7 MB

__global__ void zero_kernel(int* p, int n) {
    int i = blockIdx.x * 256 + threadIdx.x;
    if (i < n) p[i] = 0;
}

// ---- P1: per-(bucket,block) histogram of dst. No global atomics.
__global__ __launch_bounds__(256) void hist_kernel(const int* __restrict__ dst,
                                                   int* __restrict__ hist, int E, int epb) {
    __shared__ int h[NB_BUCKETS];
    int t = threadIdx.x, blk = blockIdx.x;
    if (t < NB_BUCKETS) h[t] = 0;
    __syncthreads();
    int e0 = blk * epb, e1 = min(e0 + epb, E);
    for (int e = e0 + t; e < e1; e += 256)
        atomicAdd(&h[__builtin_nontemporal_load(&dst[e]) >> BSHIFT], 1);
    __syncthreads();
    if (t < NB_BUCKETS) hist[t * NBLK + blk] = h[t];
}

// ---- P2: in-place exclusive scan of hist[196*256] (bucket-major).
__global__ __launch_bounds__(1024) void scanhist_kernel(int* __restrict__ hist) {
    const int TOT = NB_BUCKETS * NBLK;     // 50176 = 1024*49
    const int CH = TOT / 1024;             // 49
    __shared__ int s[1024];
    int t = threadIdx.x;
    int base = t * CH;
    int sum = 0;
    for (int j = 0; j < CH; ++j) sum += hist[base + j];
    int v = sum;
    s[t] = v;
    __syncthreads();
    for (int off = 1; off < 1024; off <<= 1) {
        int add = (t >= off) ? s[t - off] : 0;
        __syncthreads();
        s[t] += add;
        __syncthreads();
    }
    int run = s[t] - v;                    // exclusive prefix of this chunk
    for (int j = 0; j < CH; ++j) {
        int tmp = hist[base + j];
        hist[base + j] = run;
        run += tmp;
    }
}

// ---- P3: bin edges into bucket-grouped (src,dst) pairs.
__global__ __launch_bounds__(256) void bin_kernel(const int* __restrict__ src,
                                                  const int* __restrict__ dst,
                                                  const int* __restrict__ hist,
                                                  int2* __restrict__ pairs, int E, int epb) {
    __shared__ int cur[NB_BUCKETS];
    int t = threadIdx.x, blk = blockIdx.x;
    if (t < NB_BUCKETS) cur[t] = hist[t * NBLK + blk];
    __syncthreads();
    int e0 = blk * epb, e1 = min(e0 + epb, E);
    for (int e = e0 + t; e < e1; e += 256) {
        int d = __builtin_nontemporal_load(&dst[e]);
        int sv = __builtin_nontemporal_load(&src[e]);
        int pos = atomicAdd(&cur[d >> BSHIFT], 1);
        pairs[pos] = make_int2(sv, d);
    }
}

// ---- P4: per-bucket CSR finalize (row_ptr, dinv, col) with LDS counters.
__global__ __launch_bounds__(512) void csr_kernel(const int2* __restrict__ pairs,
                                                  const int* __restrict__ hist,
                                                  int* __restrict__ row_ptr,
                                                  float* __restrict__ dinv,
                                                  int* __restrict__ col, int E) {
    __shared__ int cntL[512];
    __shared__ int rsL[512];
    __shared__ int fillL[512];
    int t = threadIdx.x, b = blockIdx.x;
    int lo = b << BSHIFT;
    int nloc = min(512, N_NODES - lo);
    int start = hist[b * NBLK];
    int end = (b == NB_BUCKETS - 1) ? E : hist[(b + 1) * NBLK];
    cntL[t] = 0;
    fillL[t] = 0;
    __syncthreads();
    for (int e = start + t; e < end; e += 512)
        atomicAdd(&cntL[pairs[e].y - lo], 1);
    __syncthreads();
    int v = cntL[t];
    __syncthreads();
    for (int off = 1; off < 512; off <<= 1) {     // inclusive scan (Hillis-Steele)
        int add = (t >= off) ? cntL[t - off] : 0;
        __syncthreads();
        cntL[t] += add;
        __syncthreads();
    }
    int rowstart = start + cntL[t] - v;           // exclusive + bucket base
    rsL[t] = rowstart;
    if (t < nloc) {
        row_ptr[lo + t] = rowstart;
        dinv[lo + t] = rsqrtf((float)(v + 1));
    }
    if (b == NB_BUCKETS - 1 && t == 0) row_ptr[N_NODES] = E;
    __syncthreads();
    for (int e = start + t; e < end; e += 512) {
        int2 p = pairs[e];
        int dl = p.y - lo;
        int pos = rsL[dl] + atomicAdd(&fillL[dl], 1);
        col[pos] = p.x;
    }
}

__global__ void scale_x8_kernel(const float* __restrict__ x, const float* __restrict__ dinv,
                                float* __restrict__ xs, int n8) {
    int i = blockIdx.x * 256 + threadIdx.x;
    if (i < n8) xs[i] = x[i] * dinv[i >> 3];
}

// Layer-1 aggregation (D=8): unroll-8 scalar gathers, 8 nodes/wave.
__global__ void agg8_kernel(const float* __restrict__ xs, const int* __restrict__ row_ptr,
                            const int* __restrict__ col, const float* __restrict__ dinv,
                            float* __restrict__ z, int n) {
    int node = blockIdx.x * 32 + threadIdx.x / 8;
    int f = threadIdx.x % 8;
    if (node >= n) return;
    int e0 = row_ptr[node], e1 = row_ptr[node + 1];
    float a0 = xs[node * 8 + f], a1 = 0.f, a2 = 0.f, a3 = 0.f;
    float a4 = 0.f, a5 = 0.f, a6 = 0.f, a7 = 0.f;
    int e = e0;
    for (; e + 8 <= e1; e += 8) {
        int s0 = __builtin_nontemporal_load(&col[e]);
        int s1 = __builtin_nontemporal_load(&col[e + 1]);
        int s2 = __builtin_nontemporal_load(&col[e + 2]);
        int s3 = __builtin_nontemporal_load(&col[e + 3]);
        int s4 = __builtin_nontemporal_load(&col[e + 4]);
        int s5 = __builtin_nontemporal_load(&col[e + 5]);
        int s6 = __builtin_nontemporal_load(&col[e + 6]);
        int s7 = __builtin_nontemporal_load(&col[e + 7]);
        a0 += xs[s0 * 8 + f];
        a1 += xs[s1 * 8 + f];
        a2 += xs[s2 * 8 + f];
        a3 += xs[s3 * 8 + f];
        a4 += xs[s4 * 8 + f];
        a5 += xs[s5 * 8 + f];
        a6 += xs[s6 * 8 + f];
        a7 += xs[s7 * 8 + f];
    }
    for (; e < e1; ++e) a0 += xs[__builtin_nontemporal_load(&col[e]) * 8 + f];
    float r = ((a0 + a1) + (a2 + a3)) + ((a4 + a5) + (a6 + a7));
    z[node * 8 + f] = dinv[node] * r;
}

// D=64 aggregation, float4-per-lane gather. One wave per node.
// lane = j*16 + l: j = edge slot (0..3), l = feature quad (0..15).
// One vmem instruction gathers 4 edges x 256 B = 1 KB in flight (4x the
// scalar version); 8 issued per iteration -> 8 KB/wave outstanding.
// Epilogue: shfl_xor butterfly over j-groups + 256 B store from j==0 lanes.
__global__ __launch_bounds__(256) void agg64_kernel(
        const float* __restrict__ xs, const int* __restrict__ row_ptr,
        const int* __restrict__ col, const float* __restrict__ dinv,
        float* __restrict__ z, int n) {
    int wave = threadIdx.x >> 6;            // 4 waves/block = 4 nodes/block
    int node = blockIdx.x * 4 + wave;
    if (node >= n) return;
    int lane = threadIdx.x & 63;
    int j = lane >> 4, l = lane & 15;
    int e0 = row_ptr[node], e1 = row_ptr[node + 1];
    float4 acc0 = {0.f, 0.f, 0.f, 0.f}, acc1 = acc0, acc2 = acc0, acc3 = acc0;
    if (j == 0) {   // self-loop term, counted once
        const float4 sv = *reinterpret_cast<const float4*>(&xs[node * 64 + 4 * l]);
        acc0.x += sv.x; acc0.y += sv.y; acc0.z += sv.z; acc0.w += sv.w;
    }
    int base = e0;
    for (; base + 32 <= e1; base += 32) {   // 32 edges per iteration
        int s0 = __builtin_nontemporal_load(&col[base + j]);
        int s1 = __builtin_nontemporal_load(&col[base + 4 + j]);
        int s2 = __builtin_nontemporal_load(&col[base + 8 + j]);
        int s3 = __builtin_nontemporal_load(&col[base + 12 + j]);
        int s4 = __builtin_nontemporal_load(&col[base + 16 + j]);
        int s5 = __builtin_nontemporal_load(&col[base + 20 + j]);
        int s6 = __builtin_nontemporal_load(&col[base + 24 + j]);
        int s7 = __builtin_nontemporal_load(&col[base + 28 + j]);
        const float4 v0 = *reinterpret_cast<const float4*>(&xs[s0 * 64 + 4 * l]);
        const float4 v1 = *reinterpret_cast<const float4*>(&xs[s1 * 64 + 4 * l]);
        const float4 v2 = *reinterpret_cast<const float4*>(&xs[s2 * 64 + 4 * l]);
        const float4 v3 = *reinterpret_cast<const float4*>(&xs[s3 * 64 + 4 * l]);
        const float4 v4 = *reinterpret_cast<const float4*>(&xs[s4 * 64 + 4 * l]);
        const float4 v5 = *reinterpret_cast<const float4*>(&xs[s5 * 64 + 4 * l]);
        const float4 v6 = *reinterpret_cast<const float4*>(&xs[s6 * 64 + 4 * l]);
        const float4 v7 = *reinterpret_cast<const float4*>(&xs[s7 * 64 + 4 * l]);
        acc0.x += v0.x; acc0.y += v0.y; acc0.z += v0.z; acc0.w += v0.w;
        acc1.x += v1.x; acc1.y += v1.y; acc1.z += v1.z; acc1.w += v1.w;
        acc2.x += v2.x; acc2.y += v2.y; acc2.z += v2.z; acc2.w += v2.w;
        acc3.x += v3.x; acc3.y += v3.y; acc3.z += v3.z; acc3.w += v3.w;
        acc0.x += v4.x; acc0.y += v4.y; acc0.z += v4.z; acc0.w += v4.w;
        acc1.x += v5.x; acc1.y += v5.y; acc1.z += v5.z; acc1.w += v5.w;
        acc2.x += v6.x; acc2.y += v6.y; acc2.z += v6.z; acc2.w += v6.w;
        acc3.x += v7.x; acc3.y += v7.y; acc3.z += v7.z; acc3.w += v7.w;
    }
    for (; base < e1; base += 4) {          // masked 4-edge remainder
        int ee = base + j;
        int s = __builtin_nontemporal_load(&col[min(ee, e1 - 1)]);
        float m = (ee < e1) ? 1.0f : 0.0f;
        const float4 v = *reinterpret_cast<const float4*>(&xs[s * 64 + 4 * l]);
        acc0.x += m * v.x; acc0.y += m * v.y; acc0.z += m * v.z; acc0.w += m * v.w;
    }
    float4 r;
    r.x = (acc0.x + acc1.x) + (acc2.x + acc3.x);
    r.y = (acc0.y + acc1.y) + (acc2.y + acc3.y);
    r.z = (acc0.z + acc1.z) + (acc2.z + acc3.z);
    r.w = (acc0.w + acc1.w) + (acc2.w + acc3.w);
    // reduce across the 4 j-groups (lane bits 4,5)
    r.x += __shfl_xor(r.x, 16); r.y += __shfl_xor(r.y, 16);
    r.z += __shfl_xor(r.z, 16); r.w += __shfl_xor(r.w, 16);
    r.x += __shfl_xor(r.x, 32); r.y += __shfl_xor(r.y, 32);
    r.z += __shfl_xor(r.z, 32); r.w += __shfl_xor(r.w, 32);
    if (j == 0) {
        float d = dinv[node];
        r.x *= d; r.y *= d; r.z *= d; r.w *= d;
        *reinterpret_cast<float4*>(&z[node * 64 + 4 * l]) = r;
    }
}

// Y[row, :] = opt_scale(dinv[row]) * opt_relu( X[row,:] @ W + opt_bias )
template <int K, int M, bool BIAS, bool RELU, bool SCALE>
__global__ __launch_bounds__(256) void gemm_kernel(
        const float* __restrict__ X, const float* __restrict__ W,
        const float* __restrict__ b, const float* __restrict__ dinv,
        float* __restrict__ Y, int nrows) {
    constexpr int CG = M / 4;        // column groups of 4 (float4)
    constexpr int ROWS = 256 / CG;   // rows per tile
    __shared__ float Wl[K * M];
    __shared__ float Bl[M];
    __shared__ float Xl[ROWS * K];
    int tid = threadIdx.x;
    for (int i = tid; i < K * M; i += 256) Wl[i] = W[i];
    if (tid < M) {
        if constexpr (BIAS) Bl[tid] = b[tid];
        else Bl[tid] = 0.0f;
    }
    int ntiles = (nrows + ROWS - 1) / ROWS;
    for (int tile = blockIdx.x; tile < ntiles; tile += gridDim.x) {
        int row0 = tile * ROWS;
        __syncthreads();
        for (int i = tid; i < ROWS * K; i += 256) {
            int gi = row0 * K + i;
            Xl[i] = (gi < nrows * K) ? X[gi] : 0.0f;
        }
        __syncthreads();
        int r = tid / CG, cg = tid % CG;
        int row = row0 + r;
        if (row < nrows) {
            float4 acc;
            acc.x = Bl[cg * 4 + 0];
            acc.y = Bl[cg * 4 + 1];
            acc.z = Bl[cg * 4 + 2];
            acc.w = Bl[cg * 4 + 3];
#pragma unroll
            for (int k = 0; k < K; ++k) {
                float xv = Xl[r * K + k];
                const float4 w = *reinterpret_cast<const float4*>(&Wl[k * M + cg * 4]);
                acc.x += xv * w.x;
                acc.y += xv * w.y;
                acc.z += xv * w.z;
                acc.w += xv * w.w;
            }
            if constexpr (RELU) {
                acc.x = fmaxf(acc.x, 0.f); acc.y = fmaxf(acc.y, 0.f);
                acc.z = fmaxf(acc.z, 0.f); acc.w = fmaxf(acc.w, 0.f);
            }
            if constexpr (SCALE) {
                float d = dinv[row];
                acc.x *= d; acc.y *= d; acc.z *= d; acc.w *= d;
            }
            *reinterpret_cast<float4*>(&Y[row * M + cg * 4]) = acc;
        }
    }
}

// h3 = relu(z3 + b3); pool sums/counts per graph (batch sorted ->
// register-accumulate per graph-run, ~90K atomics total).
#define POOL_NPB 1024   // nodes per block
__global__ __launch_bounds__(256) void pool_kernel(
        const float* __restrict__ z3, const float* __restrict__ b3,
        const int* __restrict__ batch, float* __restrict__ sums,
        float* __restrict__ cntf, int n) {
    int wave = threadIdx.x >> 6;
    int lane = threadIdx.x & 63;   // feature index
    int node0 = blockIdx.x * POOL_NPB;
    int nodeEnd = node0 + POOL_NPB;
    if (nodeEnd > n) nodeEnd = n;
    float bias = b3[lane];
    float acc = 0.0f, cnt = 0.0f;
    int curg = -1;
    for (int node = node0 + wave; node < nodeEnd; node += 4) {
        int g = batch[node];               // wave-uniform (lane = feature)
        if (g != curg) {                   // wave-uniform branch
            if (curg >= 0) {
                atomicAdd(&sums[curg * 64 + lane], acc);
                if (lane == 0) atomicAdd(&cntf[curg], cnt);
            }
            curg = g; acc = 0.0f; cnt = 0.0f;
        }
        acc += fmaxf(__builtin_nontemporal_load(&z3[node * 64 + lane]) + bias, 0.0f);
        cnt += 1.0f;
    }
    if (curg >= 0) {
        atomicAdd(&sums[curg * 64 + lane], acc);
        if (lane == 0) atomicAdd(&cntf[curg], cnt);
    }
}

// per-graph: g = sums/max(cnt,1); hid = relu(g@Wl1+bl1); out = hid@Wl2+bl2
__global__ void mlp_kernel(const float* __restrict__ sums, const float* __restrict__ cntf,
                           const float* __restrict__ Wl1, const float* __restrict__ bl1,
                           const float* __restrict__ Wl2, const float* __restrict__ bl2,
                           float* __restrict__ out) {
    __shared__ float gv[64];
    __shared__ float hid[32];
    int g = blockIdx.x, t = threadIdx.x;
    float denom = fmaxf(cntf[g], 1.0f);
    gv[t] = sums[g * 64 + t] / denom;
    __syncthreads();
    if (t < 32) {
        float a = bl1[t];
#pragma unroll
        for (int k = 0; k < 64; ++k) a += gv[k] * Wl1[k * 32 + t];
        hid[t] = fmaxf(a, 0.0f);
    }
    __syncthreads();
    if (t == 0) {
        float o = bl2[0];
#pragma unroll
        for (int k = 0; k < 32; ++k) o += hid[k] * Wl2[k];
        out[g] = o;
    }
}

extern "C" void kernel_launch(void* const* d_in, const int* in_sizes, int n_in,
                              void* d_out, int out_size, void* d_ws, size_t ws_size,
                              hipStream_t stream) {
    const float* x   = (const float*)d_in[0];
    const int* ei    = (const int*)d_in[1];
    const int* batch = (const int*)d_in[2];
    const float* W1  = (const float*)d_in[3];
    const float* b1  = (const float*)d_in[4];
    const float* W2  = (const float*)d_in[5];
    const float* b2  = (const float*)d_in[6];
    const float* W3  = (const float*)d_in[7];
    const float* b3  = (const float*)d_in[8];
    const float* Wl1 = (const float*)d_in[9];
    const float* bl1 = (const float*)d_in[10];
    const float* Wl2 = (const float*)d_in[11];
    const float* bl2 = (const float*)d_in[12];
    float* out = (float*)d_out;

    const int N = N_NODES;
    const int E = in_sizes[1] / 2;   // 3.2M
    const int* src = ei;
    const int* dst = ei + E;

    char* ws = (char*)d_ws;
    float* sums    = (float*)(ws + OFF_SUMS);
    float* cntf    = (float*)(ws + OFF_CNTF);
    int*   hist    = (int*)(ws + OFF_HIST);
    int*   row_ptr = (int*)(ws + OFF_ROWPTR);
    float* dinv    = (float*)(ws + OFF_DINV);
    int*   col     = (int*)(ws + OFF_COL);
    float* xs1     = (float*)(ws + OFF_XS1);
    float* z1      = (float*)(ws + OFF_Z1);
    float* bufQ    = (float*)(ws + OFF_BUFQ);   // xs2, later z3
    float* bufR    = (float*)(ws + OFF_BUFR);   // z2, later ys
    float* bufP    = (float*)(ws + OFF_BUFP);   // h2
    int2*  pairs   = (int2*)(ws + OFF_PAIRS);   // aliases bufP (dead before h2)

    // zero pool accumulators
    zero_kernel<<<(ZERO_BYTES / 4 + 255) / 256, 256, 0, stream>>>((int*)ws, ZERO_BYTES / 4);

    // CSR build: hist -> scan -> bin -> per-bucket finalize
    int epb = (E + NBLK - 1) / NBLK;   // 12500
    hist_kernel<<<NBLK, 256, 0, stream>>>(dst, hist, E, epb);
    scanhist_kernel<<<1, 1024, 0, stream>>>(hist);
    bin_kernel<<<NBLK, 256, 0, stream>>>(src, dst, hist, pairs, E, epb);
    csr_kernel<<<NB_BUCKETS, 512, 0, stream>>>(pairs, hist, row_ptr, dinv, col, E);

    // Layer 1: xs1 = dinv*x ; z1 = agg(xs1) ; xs2 = dinv*relu(z1@W1+b1)
    scale_x8_kernel<<<(N * 8 + 255) / 256, 256, 0, stream>>>(x, dinv, xs1, N * 8);
    agg8_kernel<<<(N + 31) / 32, 256, 0, stream>>>(xs1, row_ptr, col, dinv, z1, N);
    gemm_kernel<8, 64, true, true, true><<<2560, 256, 0, stream>>>(z1, W1, b1, dinv, bufQ, N);

    // Layer 2: z2 = agg(xs2) ; h2 = relu(z2@W2+b2)
    agg64_kernel<<<(N + 3) / 4, 256, 0, stream>>>(bufQ, row_ptr, col, dinv, bufR, N);
    gemm_kernel<64, 128, true, true, false><<<2560, 256, 0, stream>>>(bufR, W2, b2, nullptr, bufP, N);

    // Layer 3: ys = dinv*(h2@W3) ; z3 = agg(ys)
    gemm_kernel<128, 64, false, false, true><<<2560, 256, 0, stream>>>(bufP, W3, nullptr, dinv, bufR, N);
    agg64_kernel<<<(N + 3) / 4, 256, 0, stream>>>(bufR, row_ptr, col, dinv, bufQ, N);

    // Pool + MLP head
    pool_kernel<<<(N + POOL_NPB - 1) / POOL_NPB, 256, 0, stream>>>(bufQ, b3, batch, sums, cntf, N);
    mlp_kernel<<<N_GRAPHS, 64, 0, stream>>>(sums, cntf, Wl1, bl1, Wl2, bl2, out);
}

// Round 9
// 659.489 us; speedup vs baseline: 1.5462x; 1.0151x over previous
//
#include <hip/hip_runtime.h>
#include <hip/hip_bf16.h>

#define N_NODES 100000
#define N_EDGES 3200000
#define N_GRAPHS 256
#define NB_BUCKETS 196      // ceil(100000 / 512)
#define BSHIFT 9            // 512 nodes per bucket
#define NBLK 256            // blocks for hist/bin passes
#define SCAN_BLKS 49        // 50176 / 1024

// ---------------- workspace layout (bytes) ----------------
#define OFF_SUMS      0u            // float[256*64] pool sums (zeroed)
#define OFF_CNTF      65536u        // float[256] pool counts (zeroed)
#define ZERO_BYTES    66560u
#define OFF_HIST      66560u        // int[196*256] (bucket-major) per-(bucket,block) counts
#define OFF_BSUM      267264u       // int[64] scan block sums
#define OFF_BOFF      267520u       // int[64] scan block offsets
#define OFF_ROWPTR    267776u       // int[N+1]
#define OFF_DINV      668160u       // float[N]
#define OFF_COL       1068544u      // int[E]
#define OFF_XS1       13868544u     // float[N*8]
#define OFF_Z1        17068544u     // float[N*8]
#define OFF_BUFQ      20268544u     // float[N*64]  xs2, later z3
#define OFF_BUFR      45868544u     // float[N*64]  z2, later ys
#define OFF_BUFP      71468544u     // float[N*128] h2; ALIASED: int2 pairs[E]
#define OFF_PAIRS     OFF_BUFP
// total ~122.7 MB

__global__ void zero_kernel(int* p, int n) {
    int i = blockIdx.x * 256 + threadIdx.x;
    if (i < n) p[i] = 0;
}

// ---- P1: per-(bucket,block) histogram of dst. No global atomics.
__global__ __launch_bounds__(256) void hist_kernel(const int* __restrict__ dst,
                                                   int* __restrict__ hist, int E, int epb) {
    __shared__ int h[NB_BUCKETS];
    int t = threadIdx.x, blk = blockIdx.x;
    if (t < NB_BUCKETS) h[t] = 0;
    __syncthreads();
    int e0 = blk * epb, e1 = min(e0 + epb, E);
    for (int e = e0 + t; e < e1; e += 256)
        atomicAdd(&h[__builtin_nontemporal_load(&dst[e]) >> BSHIFT], 1);
    __syncthreads();
    if (t < NB_BUCKETS) hist[t * NBLK + blk] = h[t];
}

// ---- P2: parallel exclusive scan of hist[50176] (was: ONE block doing 3
// serial passes on 1 CU -- latency-bound, est. 60-120 us hidden; now 3
// tiny kernels, ~8 us).
__global__ __launch_bounds__(1024) void scanhA_kernel(int* __restrict__ hist,
                                                      int* __restrict__ bsum) {
    __shared__ int s[1024];
    int t = threadIdx.x;
    int i = blockIdx.x * 1024 + t;     // 49*1024 == 50176 exactly
    int v = hist[i];
    s[t] = v;
    __syncthreads();
    for (int off = 1; off < 1024; off <<= 1) {
        int add = (t >= off) ? s[t - off] : 0;
        __syncthreads();
        s[t] += add;
        __syncthreads();
    }
    hist[i] = s[t] - v;                // block-local exclusive
    if (t == 1023) bsum[blockIdx.x] = s[t];
}

__global__ __launch_bounds__(64) void scanhB_kernel(const int* __restrict__ bsum,
                                                    int* __restrict__ boff) {
    __shared__ int s[64];
    int t = threadIdx.x;
    int v = (t < SCAN_BLKS) ? bsum[t] : 0;
    s[t] = v;
    __syncthreads();
    for (int off = 1; off < 64; off <<= 1) {
        int add = (t >= off) ? s[t - off] : 0;
        __syncthreads();
        s[t] += add;
        __syncthreads();
    }
    boff[t] = s[t] - v;                // exclusive
}

__global__ __launch_bounds__(1024) void scanhC_kernel(int* __restrict__ hist,
                                                      const int* __restrict__ boff) {
    int i = blockIdx.x * 1024 + threadIdx.x;
    hist[i] += boff[blockIdx.x];
}

// ---- P3: bin edges into bucket-grouped (src,dst) pairs.
__global__ __launch_bounds__(256) void bin_kernel(const int* __restrict__ src,
                                                  const int* __restrict__ dst,
                                                  const int* __restrict__ hist,
                                                  int2* __restrict__ pairs, int E, int epb) {
    __shared__ int cur[NB_BUCKETS];
    int t = threadIdx.x, blk = blockIdx.x;
    if (t < NB_BUCKETS) cur[t] = hist[t * NBLK + blk];
    __syncthreads();
    int e0 = blk * epb, e1 = min(e0 + epb, E);
    for (int e = e0 + t; e < e1; e += 256) {
        int d = __builtin_nontemporal_load(&dst[e]);
        int sv = __builtin_nontemporal_load(&src[e]);
        int pos = atomicAdd(&cur[d >> BSHIFT], 1);
        pairs[pos] = make_int2(sv, d);
    }
}

// ---- P4: per-bucket CSR finalize (row_ptr, dinv, col) with LDS counters.
__global__ __launch_bounds__(512) void csr_kernel(const int2* __restrict__ pairs,
                                                  const int* __restrict__ hist,
                                                  int* __restrict__ row_ptr,
                                                  float* __restrict__ dinv,
                                                  int* __restrict__ col, int E) {
    __shared__ int cntL[512];
    __shared__ int rsL[512];
    __shared__ int fillL[512];
    int t = threadIdx.x, b = blockIdx.x;
    int lo = b << BSHIFT;
    int nloc = min(512, N_NODES - lo);
    int start = hist[b * NBLK];
    int end = (b == NB_BUCKETS - 1) ? E : hist[(b + 1) * NBLK];
    cntL[t] = 0;
    fillL[t] = 0;
    __syncthreads();
    for (int e = start + t; e < end; e += 512)
        atomicAdd(&cntL[pairs[e].y - lo], 1);
    __syncthreads();
    int v = cntL[t];
    __syncthreads();
    for (int off = 1; off < 512; off <<= 1) {     // inclusive scan (Hillis-Steele)
        int add = (t >= off) ? cntL[t - off] : 0;
        __syncthreads();
        cntL[t] += add;
        __syncthreads();
    }
    int rowstart = start + cntL[t] - v;           // exclusive + bucket base
    rsL[t] = rowstart;
    if (t < nloc) {
        row_ptr[lo + t] = rowstart;
        dinv[lo + t] = rsqrtf((float)(v + 1));
    }
    if (b == NB_BUCKETS - 1 && t == 0) row_ptr[N_NODES] = E;
    __syncthreads();
    for (int e = start + t; e < end; e += 512) {
        int2 p = pairs[e];
        int dl = p.y - lo;
        int pos = rsL[dl] + atomicAdd(&fillL[dl], 1);
        col[pos] = p.x;
    }
}

__global__ void scale_x8_kernel(const float* __restrict__ x, const float* __restrict__ dinv,
                                float* __restrict__ xs, int n8) {
    int i = blockIdx.x * 256 + threadIdx.x;
    if (i < n8) xs[i] = x[i] * dinv[i >> 3];
}

// Layer-1 aggregation (D=8): unroll-8 scalar gathers, 8 nodes/wave.
__global__ void agg8_kernel(const float* __restrict__ xs, const int* __restrict__ row_ptr,
                            const int* __restrict__ col, const float* __restrict__ dinv,
                            float* __restrict__ z, int n) {
    int node = blockIdx.x * 32 + threadIdx.x / 8;
    int f = threadIdx.x % 8;
    if (node >= n) return;
    int e0 = row_ptr[node], e1 = row_ptr[node + 1];
    float a0 = xs[node * 8 + f], a1 = 0.f, a2 = 0.f, a3 = 0.f;
    float a4 = 0.f, a5 = 0.f, a6 = 0.f, a7 = 0.f;
    int e = e0;
    for (; e + 8 <= e1; e += 8) {
        int s0 = __builtin_nontemporal_load(&col[e]);
        int s1 = __builtin_nontemporal_load(&col[e + 1]);
        int s2 = __builtin_nontemporal_load(&col[e + 2]);
        int s3 = __builtin_nontemporal_load(&col[e + 3]);
        int s4 = __builtin_nontemporal_load(&col[e + 4]);
        int s5 = __builtin_nontemporal_load(&col[e + 5]);
        int s6 = __builtin_nontemporal_load(&col[e + 6]);
        int s7 = __builtin_nontemporal_load(&col[e + 7]);
        a0 += xs[s0 * 8 + f];
        a1 += xs[s1 * 8 + f];
        a2 += xs[s2 * 8 + f];
        a3 += xs[s3 * 8 + f];
        a4 += xs[s4 * 8 + f];
        a5 += xs[s5 * 8 + f];
        a6 += xs[s6 * 8 + f];
        a7 += xs[s7 * 8 + f];
    }
    for (; e < e1; ++e) a0 += xs[__builtin_nontemporal_load(&col[e]) * 8 + f];
    float r = ((a0 + a1) + (a2 + a3)) + ((a4 + a5) + (a6 + a7));
    z[node * 8 + f] = dinv[node] * r;
}

// D=64 aggregation, float4-per-lane gather. One wave per node.
// lane = j*16 + l: j = edge slot (0..3), l = feature quad (0..15).
__global__ __launch_bounds__(256) void agg64_kernel(
        const float* __restrict__ xs, const int* __restrict__ row_ptr,
        const int* __restrict__ col, const float* __restrict__ dinv,
        float* __restrict__ z, int n) {
    int wave = threadIdx.x >> 6;            // 4 waves/block = 4 nodes/block
    int node = blockIdx.x * 4 + wave;
    if (node >= n) return;
    int lane = threadIdx.x & 63;
    int j = lane >> 4, l = lane & 15;
    int e0 = row_ptr[node], e1 = row_ptr[node + 1];
    float4 acc0 = {0.f, 0.f, 0.f, 0.f}, acc1 = acc0, acc2 = acc0, acc3 = acc0;
    if (j == 0) {   // self-loop term, counted once
        const float4 sv = *reinterpret_cast<const float4*>(&xs[node * 64 + 4 * l]);
        acc0.x += sv.x; acc0.y += sv.y; acc0.z += sv.z; acc0.w += sv.w;
    }
    int base = e0;
    for (; base + 32 <= e1; base += 32) {   // 32 edges per iteration
        int s0 = __builtin_nontemporal_load(&col[base + j]);
        int s1 = __builtin_nontemporal_load(&col[base + 4 + j]);
        int s2 = __builtin_nontemporal_load(&col[base + 8 + j]);
        int s3 = __builtin_nontemporal_load(&col[base + 12 + j]);
        int s4 = __builtin_nontemporal_load(&col[base + 16 + j]);
        int s5 = __builtin_nontemporal_load(&col[base + 20 + j]);
        int s6 = __builtin_nontemporal_load(&col[base + 24 + j]);
        int s7 = __builtin_nontemporal_load(&col[base + 28 + j]);
        const float4 v0 = *reinterpret_cast<const float4*>(&xs[s0 * 64 + 4 * l]);
        const float4 v1 = *reinterpret_cast<const float4*>(&xs[s1 * 64 + 4 * l]);
        const float4 v2 = *reinterpret_cast<const float4*>(&xs[s2 * 64 + 4 * l]);
        const float4 v3 = *reinterpret_cast<const float4*>(&xs[s3 * 64 + 4 * l]);
        const float4 v4 = *reinterpret_cast<const float4*>(&xs[s4 * 64 + 4 * l]);
        const float4 v5 = *reinterpret_cast<const float4*>(&xs[s5 * 64 + 4 * l]);
        const float4 v6 = *reinterpret_cast<const float4*>(&xs[s6 * 64 + 4 * l]);
        const float4 v7 = *reinterpret_cast<const float4*>(&xs[s7 * 64 + 4 * l]);
        acc0.x += v0.x; acc0.y += v0.y; acc0.z += v0.z; acc0.w += v0.w;
        acc1.x += v1.x; acc1.y += v1.y; acc1.z += v1.z; acc1.w += v1.w;
        acc2.x += v2.x; acc2.y += v2.y; acc2.z += v2.z; acc2.w += v2.w;
        acc3.x += v3.x; acc3.y += v3.y; acc3.z += v3.z; acc3.w += v3.w;
        acc0.x += v4.x; acc0.y += v4.y; acc0.z += v4.z; acc0.w += v4.w;
        acc1.x += v5.x; acc1.y += v5.y; acc1.z += v5.z; acc1.w += v5.w;
        acc2.x += v6.x; acc2.y += v6.y; acc2.z += v6.z; acc2.w += v6.w;
        acc3.x += v7.x; acc3.y += v7.y; acc3.z += v7.z; acc3.w += v7.w;
    }
    for (; base < e1; base += 4) {          // masked 4-edge remainder
        int ee = base + j;
        int s = __builtin_nontemporal_load(&col[min(ee, e1 - 1)]);
        float m = (ee < e1) ? 1.0f : 0.0f;
        const float4 v = *reinterpret_cast<const float4*>(&xs[s * 64 + 4 * l]);
        acc0.x += m * v.x; acc0.y += m * v.y; acc0.z += m * v.z; acc0.w += m * v.w;
    }
    float4 r;
    r.x = (acc0.x + acc1.x) + (acc2.x + acc3.x);
    r.y = (acc0.y + acc1.y) + (acc2.y + acc3.y);
    r.z = (acc0.z + acc1.z) + (acc2.z + acc3.z);
    r.w = (acc0.w + acc1.w) + (acc2.w + acc3.w);
    // reduce across the 4 j-groups (lane bits 4,5)
    r.x += __shfl_xor(r.x, 16); r.y += __shfl_xor(r.y, 16);
    r.z += __shfl_xor(r.z, 16); r.w += __shfl_xor(r.w, 16);
    r.x += __shfl_xor(r.x, 32); r.y += __shfl_xor(r.y, 32);
    r.z += __shfl_xor(r.z, 32); r.w += __shfl_xor(r.w, 32);
    if (j == 0) {
        float d = dinv[node];
        r.x *= d; r.y *= d; r.z *= d; r.w *= d;
        *reinterpret_cast<float4*>(&z[node * 64 + 4 * l]) = r;
    }
}

// Y[row, :] = opt_scale(dinv[row]) * opt_relu( X[row,:] @ W + opt_bias )
template <int K, int M, bool BIAS, bool RELU, bool SCALE>
__global__ __launch_bounds__(256) void gemm_kernel(
        const float* __restrict__ X, const float* __restrict__ W,
        const float* __restrict__ b, const float* __restrict__ dinv,
        float* __restrict__ Y, int nrows) {
    constexpr int CG = M / 4;        // column groups of 4 (float4)
    constexpr int ROWS = 256 / CG;   // rows per tile
    __shared__ float Wl[K * M];
    __shared__ float Bl[M];
    __shared__ float Xl[ROWS * K];
    int tid = threadIdx.x;
    for (int i = tid; i < K * M; i += 256) Wl[i] = W[i];
    if (tid < M) {
        if constexpr (BIAS) Bl[tid] = b[tid];
        else Bl[tid] = 0.0f;
    }
    int ntiles = (nrows + ROWS - 1) / ROWS;
    for (int tile = blockIdx.x; tile < ntiles; tile += gridDim.x) {
        int row0 = tile * ROWS;
        __syncthreads();
        for (int i = tid; i < ROWS * K; i += 256) {
            int gi = row0 * K + i;
            Xl[i] = (gi < nrows * K) ? X[gi] : 0.0f;
        }
        __syncthreads();
        int r = tid / CG, cg = tid % CG;
        int row = row0 + r;
        if (row < nrows) {
            float4 acc;
            acc.x = Bl[cg * 4 + 0];
            acc.y = Bl[cg * 4 + 1];
            acc.z = Bl[cg * 4 + 2];
            acc.w = Bl[cg * 4 + 3];
#pragma unroll
            for (int k = 0; k < K; ++k) {
                float xv = Xl[r * K + k];
                const float4 w = *reinterpret_cast<const float4*>(&Wl[k * M + cg * 4]);
                acc.x += xv * w.x;
                acc.y += xv * w.y;
                acc.z += xv * w.z;
                acc.w += xv * w.w;
            }
            if constexpr (RELU) {
                acc.x = fmaxf(acc.x, 0.f); acc.y = fmaxf(acc.y, 0.f);
                acc.z = fmaxf(acc.z, 0.f); acc.w = fmaxf(acc.w, 0.f);
            }
            if constexpr (SCALE) {
                float d = dinv[row];
                acc.x *= d; acc.y *= d; acc.z *= d; acc.w *= d;
            }
            *reinterpret_cast<float4*>(&Y[row * M + cg * 4]) = acc;
        }
    }
}

// h3 = relu(z3 + b3); pool sums/counts per graph (batch sorted ->
// register-accumulate per graph-run, ~90K atomics total).
#define POOL_NPB 1024   // nodes per block
__global__ __launch_bounds__(256) void pool_kernel(
        const float* __restrict__ z3, const float* __restrict__ b3,
        const int* __restrict__ batch, float* __restrict__ sums,
        float* __restrict__ cntf, int n) {
    int wave = threadIdx.x >> 6;
    int lane = threadIdx.x & 63;   // feature index
    int node0 = blockIdx.x * POOL_NPB;
    int nodeEnd = node0 + POOL_NPB;
    if (nodeEnd > n) nodeEnd = n;
    float bias = b3[lane];
    float acc = 0.0f, cnt = 0.0f;
    int curg = -1;
    for (int node = node0 + wave; node < nodeEnd; node += 4) {
        int g = batch[node];               // wave-uniform (lane = feature)
        if (g != curg) {                   // wave-uniform branch
            if (curg >= 0) {
                atomicAdd(&sums[curg * 64 + lane], acc);
                if (lane == 0) atomicAdd(&cntf[curg], cnt);
            }
            curg = g; acc = 0.0f; cnt = 0.0f;
        }
        acc += fmaxf(__builtin_nontemporal_load(&z3[node * 64 + lane]) + bias, 0.0f);
        cnt += 1.0f;
    }
    if (curg >= 0) {
        atomicAdd(&sums[curg * 64 + lane], acc);
        if (lane == 0) atomicAdd(&cntf[curg], cnt);
    }
}

// per-graph: g = sums/max(cnt,1); hid = relu(g@Wl1+bl1); out = hid@Wl2+bl2
__global__ void mlp_kernel(const float* __restrict__ sums, const float* __restrict__ cntf,
                           const float* __restrict__ Wl1, const float* __restrict__ bl1,
                           const float* __restrict__ Wl2, const float* __restrict__ bl2,
                           float* __restrict__ out) {
    __shared__ float gv[64];
    __shared__ float hid[32];
    int g = blockIdx.x, t = threadIdx.x;
    float denom = fmaxf(cntf[g], 1.0f);
    gv[t] = sums[g * 64 + t] / denom;
    __syncthreads();
    if (t < 32) {
        float a = bl1[t];
#pragma unroll
        for (int k = 0; k < 64; ++k) a += gv[k] * Wl1[k * 32 + t];
        hid[t] = fmaxf(a, 0.0f);
    }
    __syncthreads();
    if (t == 0) {
        float o = bl2[0];
#pragma unroll
        for (int k = 0; k < 32; ++k) o += hid[k] * Wl2[k];
        out[g] = o;
    }
}

extern "C" void kernel_launch(void* const* d_in, const int* in_sizes, int n_in,
                              void* d_out, int out_size, void* d_ws, size_t ws_size,
                              hipStream_t stream) {
    const float* x   = (const float*)d_in[0];
    const int* ei    = (const int*)d_in[1];
    const int* batch = (const int*)d_in[2];
    const float* W1  = (const float*)d_in[3];
    const float* b1  = (const float*)d_in[4];
    const float* W2  = (const float*)d_in[5];
    const float* b2  = (const float*)d_in[6];
    const float* W3  = (const float*)d_in[7];
    const float* b3  = (const float*)d_in[8];
    const float* Wl1 = (const float*)d_in[9];
    const float* bl1 = (const float*)d_in[10];
    const float* Wl2 = (const float*)d_in[11];
    const float* bl2 = (const float*)d_in[12];
    float* out = (float*)d_out;

    const int N = N_NODES;
    const int E = in_sizes[1] / 2;   // 3.2M
    const int* src = ei;
    const int* dst = ei + E;

    char* ws = (char*)d_ws;
    float* sums    = (float*)(ws + OFF_SUMS);
    float* cntf    = (float*)(ws + OFF_CNTF);
    int*   hist    = (int*)(ws + OFF_HIST);
    int*   bsum    = (int*)(ws + OFF_BSUM);
    int*   boff    = (int*)(ws + OFF_BOFF);
    int*   row_ptr = (int*)(ws + OFF_ROWPTR);
    float* dinv    = (float*)(ws + OFF_DINV);
    int*   col     = (int*)(ws + OFF_COL);
    float* xs1     = (float*)(ws + OFF_XS1);
    float* z1      = (float*)(ws + OFF_Z1);
    float* bufQ    = (float*)(ws + OFF_BUFQ);   // xs2, later z3
    float* bufR    = (float*)(ws + OFF_BUFR);   // z2, later ys
    float* bufP    = (float*)(ws + OFF_BUFP);   // h2
    int2*  pairs   = (int2*)(ws + OFF_PAIRS);   // aliases bufP (dead before h2)

    // zero pool accumulators
    zero_kernel<<<(ZERO_BYTES / 4 + 255) / 256, 256, 0, stream>>>((int*)ws, ZERO_BYTES / 4);

    // CSR build: hist -> parallel scan (A/B/C) -> bin -> per-bucket finalize
    int epb = (E + NBLK - 1) / NBLK;   // 12500
    hist_kernel<<<NBLK, 256, 0, stream>>>(dst, hist, E, epb);
    scanhA_kernel<<<SCAN_BLKS, 1024, 0, stream>>>(hist, bsum);
    scanhB_kernel<<<1, 64, 0, stream>>>(bsum, boff);
    scanhC_kernel<<<SCAN_BLKS, 1024, 0, stream>>>(hist, boff);
    bin_kernel<<<NBLK, 256, 0, stream>>>(src, dst, hist, pairs, E, epb);
    csr_kernel<<<NB_BUCKETS, 512, 0, stream>>>(pairs, hist, row_ptr, dinv, col, E);

    // Layer 1: xs1 = dinv*x ; z1 = agg(xs1) ; xs2 = dinv*relu(z1@W1+b1)
    scale_x8_kernel<<<(N * 8 + 255) / 256, 256, 0, stream>>>(x, dinv, xs1, N * 8);
    agg8_kernel<<<(N + 31) / 32, 256, 0, stream>>>(xs1, row_ptr, col, dinv, z1, N);
    gemm_kernel<8, 64, true, true, true><<<2560, 256, 0, stream>>>(z1, W1, b1, dinv, bufQ, N);

    // Layer 2: z2 = agg(xs2) ; h2 = relu(z2@W2+b2)
    agg64_kernel<<<(N + 3) / 4, 256, 0, stream>>>(bufQ, row_ptr, col, dinv, bufR, N);
    gemm_kernel<64, 128, true, true, false><<<2560, 256, 0, stream>>>(bufR, W2, b2, nullptr, bufP, N);

    // Layer 3: ys = dinv*(h2@W3) ; z3 = agg(ys)
    gemm_kernel<128, 64, false, false, true><<<2560, 256, 0, stream>>>(bufP, W3, nullptr, dinv, bufR, N);
    agg64_kernel<<<(N + 3) / 4, 256, 0, stream>>>(bufR, row_ptr, col, dinv, bufQ, N);

    // Pool + MLP head
    pool_kernel<<<(N + POOL_NPB - 1) / POOL_NPB, 256, 0, stream>>>(bufQ, b3, batch, sums, cntf, N);
    mlp_kernel<<<N_GRAPHS, 64, 0, stream>>>(sums, cntf, Wl1, bl1, Wl2, bl2, out);
}